// Round 6
// baseline (5760.411 us; speedup 1.0000x reference)
//
#include <hip/hip_runtime.h>
#include <math.h>

typedef unsigned short u16;
typedef float v4f  __attribute__((ext_vector_type(4)));
typedef __bf16 v8bf __attribute__((ext_vector_type(8)));

enum { nB=4, nL=1024, nW=1024, nH=16, nN=64, nE=2048, nP=128, nNH=32, nDEPTH=4 };

__device__ __forceinline__ float bf2f(u16 u){ unsigned v=((unsigned)u)<<16; return __builtin_bit_cast(float,v); }
__device__ __forceinline__ u16 f2bf(float f){ unsigned x=__builtin_bit_cast(unsigned,f); return (u16)((x + 0x7fffu + ((x>>16)&1u))>>16); }
__device__ __forceinline__ float softplus_f(float v){ return (v>15.f)? v : log1pf(expf(v)); }
__device__ __forceinline__ void unp8(uint4 u, float* f){
  f[0]=bf2f((u16)(u.x&0xffff)); f[1]=bf2f((u16)(u.x>>16));
  f[2]=bf2f((u16)(u.y&0xffff)); f[3]=bf2f((u16)(u.y>>16));
  f[4]=bf2f((u16)(u.z&0xffff)); f[5]=bf2f((u16)(u.z>>16));
  f[6]=bf2f((u16)(u.w&0xffff)); f[7]=bf2f((u16)(u.w>>16));
}
__device__ __forceinline__ v4f unp4(ushort4 u){
  v4f r = {bf2f(u.x), bf2f(u.y), bf2f(u.z), bf2f(u.w)}; return r;
}

// ---------------- copy h (fp32) -> x (fp32 residual) ----------------
__global__ void k_cvt(const float* __restrict__ hsrc, float* __restrict__ x){
  int i = (blockIdx.x*256 + threadIdx.x)*4;
  *(v4f*)(x + i) = *(const v4f*)(hsrc + i);
}

// ---------------- transpose fp32 (R,C) -> bf16 (C,R) ----------------
__global__ __launch_bounds__(256) void k_transpose(const float* __restrict__ src, u16* __restrict__ dst,
    int R, int C)
{
  __shared__ u16 tl[32][36];
  int r0 = blockIdx.y*32, c0 = blockIdx.x*32;
  int tid = threadIdx.x;
  int r = tid>>3, c4 = (tid&7)*4;
  if (r0 + r < R){
#pragma unroll
    for (int jj=0;jj<4;jj++){
      int c = c0 + c4 + jj;
      tl[r][c4+jj] = (c < C) ? f2bf(src[(size_t)(r0+r)*C + c]) : (u16)0;
    }
  }
  __syncthreads();
  int c = tid>>3, r4 = (tid&7)*4;
  if (c0 + c < C){
#pragma unroll
    for (int jj=0;jj<4;jj++){
      int rr = r0 + r4 + jj;
      if (rr < R) dst[(size_t)(c0+c)*R + rr] = tl[r4+jj][c];
    }
  }
}

// ---------------- rmsnorm: x(fp32) * w(fp32) -> bf16 and/or fp32 ----------------
__global__ __launch_bounds__(256) void k_rmsnorm(const float* __restrict__ x, const float* __restrict__ w,
    u16* __restrict__ obf, float* __restrict__ of32)
{
  int row = blockIdx.x, tid = threadIdx.x;
  const float* xr = x + (size_t)row*1024;
  v4f v = *(const v4f*)(xr + tid*4);
  float ss = v[0]*v[0]+v[1]*v[1]+v[2]*v[2]+v[3]*v[3];
#pragma unroll
  for (int o=1;o<64;o<<=1) ss += __shfl_xor(ss,o);
  __shared__ float red[4];
  if ((tid&63)==0) red[tid>>6] = ss;
  __syncthreads();
  float tot = red[0]+red[1]+red[2]+red[3];
  float rms = rsqrtf(tot*(1.f/1024.f) + 1e-6f);
  v4f wv = *(const v4f*)(w + tid*4);
  float o0=v[0]*rms*wv[0], o1=v[1]*rms*wv[1], o2=v[2]*rms*wv[2], o3=v[3]*rms*wv[3];
  if (obf){
    ushort4 ob = { f2bf(o0), f2bf(o1), f2bf(o2), f2bf(o3) };
    *(ushort4*)(obf + (size_t)row*1024 + tid*4) = ob;
  }
  if (of32){
    v4f ov = {o0,o1,o2,o3};
    *(v4f*)(of32 + (size_t)row*1024 + tid*4) = ov;
  }
}

// ---------------- MFMA GEMM: C = A(MxK,bf16) @ BT(NxK,bf16)^T + bias(fp32); OT float(+=) or u16
template<typename OT, bool ADD>
__global__ __launch_bounds__(256) void k_gemm(const u16* __restrict__ A, const u16* __restrict__ BT,
    const float* __restrict__ bias, OT* __restrict__ C, int N, int K)
{
  __shared__ u16 As[128*40];
  __shared__ u16 Bs[128*40];
  const int tid = threadIdx.x;
  const int wave = tid>>6, lane = tid&63, quad = lane>>4, l15 = lane&15;
  const int bm = blockIdx.y*128, bn = blockIdx.x*128;
  const int wm = (wave>>1)*64, wn = (wave&1)*64;
  v4f acc[4][4];
#pragma unroll
  for (int i=0;i<4;i++)
#pragma unroll
    for (int j=0;j<4;j++){ v4f z = {0.f,0.f,0.f,0.f}; acc[i][j]=z; }

  for (int k0=0; k0<K; k0+=32){
    uint4 av[2], bv[2];
#pragma unroll
    for (int i=0;i<2;i++){
      int c = 2*tid+i, row = c>>2, pos = c&3;
      av[i] = *(const uint4*)(A  + (size_t)(bm+row)*K + k0 + pos*8);
      bv[i] = *(const uint4*)(BT + (size_t)(bn+row)*K + k0 + pos*8);
    }
    __syncthreads();
#pragma unroll
    for (int i=0;i<2;i++){
      int c = 2*tid+i, row = c>>2, pos = c&3;
      *(uint4*)(As + row*40 + pos*8) = av[i];
      *(uint4*)(Bs + row*40 + pos*8) = bv[i];
    }
    __syncthreads();
    v8bf af[4], bfr[4];
#pragma unroll
    for (int mi=0;mi<4;mi++) af[mi]  = *(const v8bf*)(As + (wm+mi*16+l15)*40 + quad*8);
#pragma unroll
    for (int ni=0;ni<4;ni++) bfr[ni] = *(const v8bf*)(Bs + (wn+ni*16+l15)*40 + quad*8);
#pragma unroll
    for (int mi=0;mi<4;mi++)
#pragma unroll
      for (int ni=0;ni<4;ni++)
        acc[mi][ni] = __builtin_amdgcn_mfma_f32_16x16x32_bf16(af[mi], bfr[ni], acc[mi][ni], 0,0,0);
  }
#pragma unroll
  for (int ni=0;ni<4;ni++){
    int col = bn + wn + ni*16 + l15;
    float bz = bias[col];
#pragma unroll
    for (int mi=0;mi<4;mi++){
      int row = bm + wm + mi*16 + quad*4;
      v4f v = acc[mi][ni];
#pragma unroll
      for (int r=0;r<4;r++){
        size_t off = (size_t)(row+r)*N + col;
        float o = v[r] + bz;
        if constexpr (ADD) o += ((const float*)C)[off];
        if constexpr (sizeof(OT)==2) ((u16*)C)[off] = f2bf(o);
        else ((float*)C)[off] = o;
      }
    }
  }
}

// ---------------- dt matmul: dtraw(rows x 16) = r(bf16) @ dt_wT(16x1024,bf16)^T --------------
__global__ __launch_bounds__(64) void k_dt(const u16* __restrict__ r, const u16* __restrict__ dtwT,
    float* __restrict__ dtraw)
{
  int row = blockIdx.x, lane = threadIdx.x;
  const u16* rp = r + (size_t)row*1024 + lane*16;
  float rv[16];
  unp8(*(const uint4*)rp, rv);
  unp8(*(const uint4*)(rp+8), rv+8);
  float keep = 0.f;
  for (int hh=0; hh<16; hh++){
    const u16* wp = dtwT + hh*1024 + lane*16;
    float wv[16];
    unp8(*(const uint4*)wp, wv);
    unp8(*(const uint4*)(wp+8), wv+8);
    float sv = 0.f;
#pragma unroll
    for (int j=0;j<16;j++) sv = fmaf(rv[j], wv[j], sv);
#pragma unroll
    for (int o=1;o<64;o<<=1) sv += __shfl_xor(sv, o);
    if (lane==hh) keep = sv;
  }
  if (lane<16) dtraw[(size_t)row*16 + lane] = keep;
}

// ---------------- prep2 per (b,l,h): scal2 = (dec, 0.5*dt); dtarr = dt ----------------
__global__ void k_prep2(const float* __restrict__ dtraw, const float* __restrict__ dt_b,
    const float* __restrict__ A_log, float* __restrict__ scal2, float* __restrict__ dtarr)
{
  int i = blockIdx.x*256 + threadIdx.x;      // (b,l,h) h-fastest
  int h = i & 15;
  float dt0 = fminf(softplus_f(dtraw[i] + dt_b[h]), 30.f);
  float A = -expf(A_log[h]);
  scal2[(size_t)i*2]   = expf(A*dt0);
  scal2[(size_t)i*2+1] = 0.5f*dt0;
  dtarr[i] = dt0;
}

// ---------------- cs2: per-step cos/sin only ----------------
__global__ void k_cs2(const float* __restrict__ dtarr, const float* __restrict__ omega,
    float* __restrict__ cst, float* __restrict__ sst)
{
  int i = blockIdx.x*256 + threadIdx.x;   // (b,l,h,q)
  int q = i & 31, blh = i>>5;
  float sn, cn; __sincosf(dtarr[blh]*omega[q], &sn, &cn);
  cst[i]=cn; sst[i]=sn;
}

// ---------------- direct scan: exact reference recurrence, one block per (b,h) ------------
__global__ __launch_bounds__(256) void k_scan_direct(const u16* __restrict__ xz, const u16* __restrict__ bcb,
    const float* __restrict__ scal2, const float* __restrict__ cst, const float* __restrict__ sst,
    const float* __restrict__ Dsk, float* __restrict__ y)
{
  int bh = blockIdx.x; int b = bh>>4, h = bh&15;
  int t = threadIdx.x, p = t>>1, half = t&1, q0 = half*16;
  float h1[16], h2[16], B1p[16], B2p[16];
#pragma unroll
  for (int j=0;j<16;j++){ h1[j]=0.f; h2[j]=0.f; B1p[j]=0.f; B2p[j]=0.f; }
  float xprev = 0.f;
  float Dskip = Dsk[h];
  size_t rowbase = (size_t)b*nL;
  const u16* xp = xz + rowbase*4096 + h*128 + p;
  const u16* Bp = bcb + rowbase*2048 + h*64 + q0;
  const u16* Cp = Bp + 1024;
  const float* sc = scal2 + (rowbase*16 + h)*2;
  const float* cp = cst + (rowbase*16 + h)*32 + q0;
  const float* sp = sst + (rowbase*16 + h)*32 + q0;
  float* yp = y + rowbase*2048 + h*128 + p;
  for (int l=0; l<nL; l++){
    float dec = sc[0], hdt = sc[1];
    float xv = bf2f(*xp);
    float dxp = dec * xprev;
    float Bn1[16], Bn2[16], Cn1[16], Cn2[16], cv[16], sv[16];
    unp8(*(const uint4*)(Bp),    Bn1);  unp8(*(const uint4*)(Bp+8),    Bn1+8);
    unp8(*(const uint4*)(Bp+32), Bn2);  unp8(*(const uint4*)(Bp+40),   Bn2+8);
    unp8(*(const uint4*)(Cp),    Cn1);  unp8(*(const uint4*)(Cp+8),    Cn1+8);
    unp8(*(const uint4*)(Cp+32), Cn2);  unp8(*(const uint4*)(Cp+40),   Cn2+8);
#pragma unroll
    for (int j4=0;j4<4;j4++){
      v4f c4 = *(const v4f*)(cp + 4*j4);
      v4f s4 = *(const v4f*)(sp + 4*j4);
#pragma unroll
      for (int j=0;j<4;j++){ cv[4*j4+j]=c4[j]; sv[4*j4+j]=s4[j]; }
    }
    float yacc = 0.f;
#pragma unroll
    for (int j=0;j<16;j++){
      float c = cv[j], s = sv[j];
      float rh1 = h1[j]*c - h2[j]*s;
      float rh2 = h1[j]*s + h2[j]*c;
      float rb1 = B1p[j]*c - B2p[j]*s;
      float rb2 = B1p[j]*s + B2p[j]*c;
      float nh1 = fmaf(dec, rh1, hdt*fmaf(dxp, rb1, xv*Bn1[j]));
      float nh2 = fmaf(dec, rh2, hdt*fmaf(dxp, rb2, xv*Bn2[j]));
      h1[j]=nh1; h2[j]=nh2;
      B1p[j]=Bn1[j]; B2p[j]=Bn2[j];
      yacc = fmaf(nh1, Cn1[j], fmaf(nh2, Cn2[j], yacc));
    }
    xprev = xv;
    yacc += __shfl_xor(yacc, 1);
    if (half==0) *yp = fmaf(xv, Dskip, yacc);
    xp += 4096; Bp += 2048; Cp += 2048; sc += 32; cp += 512; sp += 512; yp += 2048;
  }
}

// ---------------- gate: g = y * silu(z)  -> bf16 (internal) ----------------
__global__ void k_gate(const float* __restrict__ y, const u16* __restrict__ xz, u16* __restrict__ gbuf){
  int e0 = (blockIdx.x*256 + threadIdx.x)*4;
  int rw = e0 >> 11, col = e0 & 2047;
  v4f yv = *(const v4f*)(y + e0);
  v4f zv = unp4(*(const ushort4*)(xz + (size_t)rw*4096 + 2048 + col));
  ushort4 ob;
  float z0=zv[0], z1=zv[1], z2=zv[2], z3=zv[3];
  ob.x = f2bf(yv[0]*z0/(1.f+expf(-z0)));
  ob.y = f2bf(yv[1]*z1/(1.f+expf(-z1)));
  ob.z = f2bf(yv[2]*z2/(1.f+expf(-z2)));
  ob.w = f2bf(yv[3]*z3/(1.f+expf(-z3)));
  *(ushort4*)(gbuf + e0) = ob;
}

// ---------------- attention logits: attn[b,l] = q . xn[b,l] / 32 ----------------
__global__ __launch_bounds__(256) void k_attn(const float* __restrict__ xn, const float* __restrict__ q,
    float* __restrict__ attn)
{
  int wid = blockIdx.x*4 + (threadIdx.x>>6);
  int lane = threadIdx.x & 63;
  const float* xr = xn + (size_t)wid*1024 + lane*16;
  const float* qr = q + lane*16;
  float sAcc=0.f;
#pragma unroll
  for (int j4=0;j4<4;j4++){
    v4f xv = *(const v4f*)(xr + 4*j4);
    v4f qv = *(const v4f*)(qr + 4*j4);
#pragma unroll
    for (int j=0;j<4;j++) sAcc = fmaf(xv[j], qv[j], sAcc);
  }
#pragma unroll
  for (int o=1;o<64;o<<=1) sAcc += __shfl_xor(sAcc,o);
  if (lane==0) attn[wid] = sAcc*(1.f/32.f);
}

// ---------------- softmax over L + pooled[b,w] ----------------
__global__ __launch_bounds__(1024) void k_pool(const float* __restrict__ attn, const float* __restrict__ xn,
    float* __restrict__ pooled)
{
  int b = blockIdx.x, t = threadIdx.x;
  __shared__ float ash[1024];
  __shared__ float red[16];
  __shared__ float red2[16];
  float av = attn[b*1024 + t];
  float m = av;
#pragma unroll
  for (int o=1;o<64;o<<=1) m = fmaxf(m, __shfl_xor(m,o));
  if ((t&63)==0) red[t>>6] = m;
  __syncthreads();
  float bm = red[0];
  for (int jj=1;jj<16;jj++) bm = fmaxf(bm, red[jj]);
  float e = expf(av - bm);
  ash[t] = e;
  float sm = e;
#pragma unroll
  for (int o=1;o<64;o<<=1) sm += __shfl_xor(sm,o);
  if ((t&63)==0) red2[t>>6] = sm;
  __syncthreads();
  float tot = 0.f;
  for (int jj=0;jj<16;jj++) tot += red2[jj];
  float inv = 1.f/tot;
  float acc = 0.f;
  for (int l=0;l<1024;l++) acc = fmaf(ash[l], xn[((size_t)b*1024 + l)*1024 + t], acc);
  pooled[(size_t)b*1024 + t] = acc*inv;
}

// ---------------- heads: 96 outputs (16 features then 80 biases), fp32 in, FP32 OUT -------
__global__ __launch_bounds__(256) void k_heads(const float* __restrict__ pooled,
    const float* __restrict__ fw, const float* __restrict__ fb,
    const float* __restrict__ bw, const float* __restrict__ bb, float* __restrict__ outp)
{
  int o = blockIdx.x, t = threadIdx.x;
  int b, j, NJ; const float *Wp, *Bp;
  if (o < 16){ b = o>>2; j = o&3; NJ = 4; Wp = fw; Bp = fb; }
  else { int oo = o-16; b = oo/20; j = oo - b*20; NJ = 20; Wp = bw; Bp = bb; }
  v4f pv = *(const v4f*)(pooled + (size_t)b*1024 + t*4);
  int w0 = t*4;
  float sAcc = pv[0]*Wp[(size_t)(w0+0)*NJ + j] + pv[1]*Wp[(size_t)(w0+1)*NJ + j]
             + pv[2]*Wp[(size_t)(w0+2)*NJ + j] + pv[3]*Wp[(size_t)(w0+3)*NJ + j];
#pragma unroll
  for (int of=1; of<64; of<<=1) sAcc += __shfl_xor(sAcc, of);
  __shared__ float red[4];
  if ((t&63)==0) red[t>>6] = sAcc;
  __syncthreads();
  if (t==0) outp[o] = red[0]+red[1]+red[2]+red[3] + Bp[j];   // fp32 output — d_out is float*
}

extern "C" void kernel_launch(void* const* d_in, const int* in_sizes, int n_in,
                              void* d_out, int out_size, void* d_ws, size_t ws_size,
                              hipStream_t stream)
{
  (void)n_in; (void)out_size;
  int base = (in_sizes[2] >= 1000000) ? 1 : 2;   // index of ln_w (mask present -> 2)
  const float* h_in   = (const float*)d_in[0];
  const float* ln_w   = (const float*)d_in[base+0];
  const float* in_w   = (const float*)d_in[base+1];
  const float* in_b   = (const float*)d_in[base+2];
  const float* dt_w   = (const float*)d_in[base+3];
  const float* dt_b   = (const float*)d_in[base+4];
  const float* bc_w   = (const float*)d_in[base+5];
  const float* bc_b   = (const float*)d_in[base+6];
  const float* A_log  = (const float*)d_in[base+7];
  const float* omega  = (const float*)d_in[base+8];
  const float* D_skip = (const float*)d_in[base+9];
  const float* out_w  = (const float*)d_in[base+10];
  const float* out_b  = (const float*)d_in[base+11];
  const float* fln_w  = (const float*)d_in[base+12];
  const float* queries= (const float*)d_in[base+13];
  const float* feat_w = (const float*)d_in[base+14];
  const float* feat_b = (const float*)d_in[base+15];
  const float* bias_w = (const float*)d_in[base+16];
  const float* bias_b = (const float*)d_in[base+17];

  char* w0 = (char*)d_ws;
  size_t off = 0;
  auto take = [&](size_t bytes)->char*{ char* pp = w0 + off; off += (bytes + 255) & ~(size_t)255; return pp; };
  u16* wT_in  = (u16*)take((size_t)4096*1024*2);
  u16* wT_bc  = (u16*)take((size_t)2048*1024*2);
  u16* wT_out = (u16*)take((size_t)1024*2048*2);
  u16* wT_dt  = (u16*)take((size_t)16*1024*2);
  float* x    = (float*)take((size_t)4194304*4);
  u16* rbf    = (u16*)take((size_t)4194304*2);
  u16* xz     = (u16*)take((size_t)16777216*2);
  u16* bcb    = (u16*)take((size_t)8388608*2);
  float* ybuf = (float*)take((size_t)8388608*4);
  u16* gbuf   = (u16*)take((size_t)8388608*2);
  float* cst  = (float*)take((size_t)2097152*4);
  float* sst  = (float*)take((size_t)2097152*4);
  float* dtraw= (float*)take((size_t)65536*4);
  float* dtarr= (float*)take((size_t)65536*4);
  float* scal2= (float*)take((size_t)65536*8);
  float* attnb= (float*)take((size_t)4096*4);
  float* pool = (float*)take((size_t)4096*4);
  if (off > ws_size) return;   // insufficient scratch: fail cleanly, not a fault
  float* xn   = ybuf;          // alias (ybuf dead after last gate)

  k_cvt<<<4096,256,0,stream>>>(h_in, x);
  for (int d=0; d<4; d++){
    k_transpose<<<dim3(128,32),256,0,stream>>>(in_w + (size_t)d*1024*4096, wT_in, 1024, 4096);
    k_transpose<<<dim3(64,32),256,0,stream>>>(bc_w + (size_t)d*1024*2048, wT_bc, 1024, 2048);
    k_transpose<<<dim3(32,64),256,0,stream>>>(out_w + (size_t)d*2048*1024, wT_out, 2048, 1024);
    k_transpose<<<dim3(1,32),256,0,stream>>>(dt_w + (size_t)d*1024*16, wT_dt, 1024, 16);
    k_rmsnorm<<<4096,256,0,stream>>>(x, ln_w + d*1024, rbf, (float*)nullptr);
    k_gemm<u16,false><<<dim3(32,32),256,0,stream>>>(rbf, wT_in, in_b + d*4096, xz, 4096, 1024);
    k_gemm<u16,false><<<dim3(16,32),256,0,stream>>>(rbf, wT_bc, bc_b + d*2048, bcb, 2048, 1024);
    k_dt<<<4096,64,0,stream>>>(rbf, wT_dt, dtraw);
    k_prep2<<<256,256,0,stream>>>(dtraw, dt_b + d*16, A_log + d*16, scal2, dtarr);
    k_cs2<<<8192,256,0,stream>>>(dtarr, omega + d*32, cst, sst);
    k_scan_direct<<<64,256,0,stream>>>(xz, bcb, scal2, cst, sst, D_skip + d*16, ybuf);
    k_gate<<<8192,256,0,stream>>>(ybuf, xz, gbuf);
    k_gemm<float,true><<<dim3(8,32),256,0,stream>>>(gbuf, wT_out, out_b + d*1024, x, 1024, 2048);
  }
  k_rmsnorm<<<4096,256,0,stream>>>(x, fln_w, (u16*)nullptr, xn);
  k_attn<<<1024,256,0,stream>>>(xn, queries, attnb);
  k_pool<<<4,1024,0,stream>>>(attnb, xn, pool);
  k_heads<<<96,256,0,stream>>>(pool, feat_w, feat_b, bias_w, bias_b, (float*)d_out);
}